// Round 2
// baseline (549.067 us; speedup 1.0000x reference)
//
#include <hip/hip_runtime.h>

#define H  64
#define TT 512
#define BB 512
#define CSTR 80             // hbuf chain stride in halves
#define UCH 16              // chunk length (steps)
#define XROW 260            // xp row stride in f32 (mult of 4: 16B-aligned b128 reads)
#define XCH  (UCH*XROW + 8) // per-chain xp stride (+8 dw: chains land on different banks)
#define NCHUNK (TT / UCH)

typedef _Float16 half8 __attribute__((ext_vector_type(8)));
typedef _Float16 half4 __attribute__((ext_vector_type(4)));
typedef float    f32x4 __attribute__((ext_vector_type(4)));

#define LOG2E 1.4426950408889634f
#define TWOL  2.8853900817779268f
#define FOURL 5.7707801635558536f

__device__ __forceinline__ float frcp(float x) { return __builtin_amdgcn_rcpf(x); }
__device__ __forceinline__ float ex2(float x)  { return __builtin_amdgcn_exp2f(x); }

// Barrier waiting ONLY lgkmcnt (LDS visibility) — keeps global stores/prefetch
// loads (vmcnt) off the per-step critical path.
__device__ __forceinline__ void step_barrier() {
    asm volatile("s_waitcnt lgkmcnt(0)\n\ts_barrier" ::: "memory");
}

// ---------------------------------------------------------------------------
// xpad: [B*T][32] fp16, cols 0..3 = x, cols 4..31 = 0.
// ---------------------------------------------------------------------------
__global__ __launch_bounds__(256) void xpad_prep(const float* __restrict__ x,
                                                 _Float16* __restrict__ xpad) {
    int gid = blockIdx.x * 256 + threadIdx.x;
    int row = gid >> 2, q = gid & 3;
    half8 v = {0,0,0,0,0,0,0,0};
    if (q == 0) {
        float4 xv = ((const float4*)x)[row];
        v[0] = (_Float16)xv.x; v[1] = (_Float16)xv.y;
        v[2] = (_Float16)xv.z; v[3] = (_Float16)xv.w;
    }
    *(half8*)(xpad + (size_t)row * 32 + q * 8) = v;
}

// ---------------------------------------------------------------------------
// Layer 0. 4 samples/block (one dir), grid 256 = 1 block/CU.
// TYPE-MAJOR phase B: MFMA pair t computes gate-type t for units w*16+0..15.
// Lane (q,m): chain = m&3 (cols 4 chains x 4 replicas), owns units w*16+q*4+i
// with all 4 gate types from the 4 pairs' D regs -> no select cascade; sigma
// chains overlap MFMA issue. Weights pre-scaled by -log2e (i,f,o) / +2log2e (g);
// cell state kept in 2log2e*c domain.
// Phase A: col n -> Wih row n (type-major is the native row order); the col
// type n>>6 == w, so the scale is wave-uniform. xp is cross-wave now ->
// one extra barrier per chunk.
// ---------------------------------------------------------------------------
__global__ __launch_bounds__(256, 1) void lstm_l0(
    const _Float16* __restrict__ xpad,
    const float* __restrict__ WihF, const float* __restrict__ WhhF, const float* __restrict__ bF,
    const float* __restrict__ WihB, const float* __restrict__ WhhB, const float* __restrict__ bB,
    _Float16* __restrict__ out0)
{
    const int dir = blockIdx.x & 1;
    const int b0  = (blockIdx.x >> 1) * 4;
    const int tid = threadIdx.x;
    const int w = tid >> 6, l = tid & 63, m = l & 15, q = l >> 4;
    const int ch = m & 3;

    const float* Wih = dir ? WihB : WihF;
    const float* Whh = dir ? WhhB : WhhF;
    const float* bia = dir ? bB   : bF;

    // Recurrent weights, type-major: Ah[t] rows = units w*16+r, gate type t.
    half8 Ah[4][2];
#pragma unroll
    for (int t = 0; t < 4; ++t) {
        const float st = (t == 2) ? TWOL : -LOG2E;
        const int wrow = t * 64 + w * 16 + m;
#pragma unroll
        for (int s2 = 0; s2 < 2; ++s2) {
            const float* src = Whh + wrow * 64 + s2 * 32 + q * 8;
            half8 tmp;
#pragma unroll
            for (int j = 0; j < 8; ++j) tmp[j] = (_Float16)(src[j] * st);
            Ah[t][s2] = tmp;
        }
    }

    // Phase-A weights: col n = w*64+j*16+m -> Wih row n; type n>>6 == w.
    const float sw = (w == 2) ? TWOL : -LOG2E;
    half8 Bg[4];
    float bvj[4];
#pragma unroll
    for (int j = 0; j < 4; ++j) {
        const int n = w * 64 + j * 16 + m;
        bvj[j] = bia[n] * sw;
        half8 tmp;
#pragma unroll
        for (int jj = 0; jj < 8; ++jj) {
            int k = q * 8 + jj;
            tmp[jj] = (k < 4) ? (_Float16)(Wih[n * 4 + k] * sw) : (_Float16)0.f;
        }
        Bg[j] = tmp;
    }

    __shared__ __align__(16) float xp[4 * XCH];            // ~66.7 KB
    __shared__ __align__(16) _Float16 hbuf[2][4][CSTR];
    for (int i = tid; i < 2 * 4 * CSTR / 2; i += 256) ((unsigned int*)hbuf)[i] = 0u;
    __syncthreads();

    float cp[4] = {0.f, 0.f, 0.f, 0.f};   // cell state, 2log2e-scaled domain
    int p = 0;

    half8 a[4];
    {
        const int tA = dir ? (TT - 1 - m) : m;
#pragma unroll
        for (int cc = 0; cc < 4; ++cc)
            a[cc] = *(const half8*)(xpad + (size_t)((b0 + cc) * TT + tA) * 32 + q * 8);
    }

    for (int chunk = 0; chunk < NCHUNK; ++chunk) {
        const int c0 = chunk * UCH;

        // Phase A
#pragma unroll
        for (int cc = 0; cc < 4; ++cc) {
#pragma unroll
            for (int j = 0; j < 4; ++j) {
                f32x4 acc = {bvj[j], bvj[j], bvj[j], bvj[j]};
                acc = __builtin_amdgcn_mfma_f32_16x16x32_f16(a[cc], Bg[j], acc, 0, 0, 0);
#pragma unroll
                for (int i = 0; i < 4; ++i)
                    xp[cc * XCH + (q * 4 + i) * XROW + w * 64 + j * 16 + m] = acc[i];
            }
        }
        if (chunk + 1 < NCHUNK) {
            const int tA = dir ? (TT - 1 - (c0 + UCH + m)) : (c0 + UCH + m);
#pragma unroll
            for (int cc = 0; cc < 4; ++cc)
                a[cc] = *(const half8*)(xpad + (size_t)((b0 + cc) * TT + tA) * 32 + q * 8);
        }
        step_barrier();   // xp is cross-wave (phase-B reads all 4 type blocks)

        // Phase B
        f32x4 xv[4];
#pragma unroll
        for (int t = 0; t < 4; ++t)
            xv[t] = *(const f32x4*)&xp[ch * XCH + t * 64 + w * 16 + q * 4];

        for (int u = 0; u < UCH; ++u) {
            half8 ah0 = *(const half8*)&hbuf[p][ch][q * 8];
            half8 ah1 = *(const half8*)&hbuf[p][ch][32 + q * 8];

            const int un = (u + 1 < UCH) ? (u + 1) : u;
            f32x4 xn[4];
#pragma unroll
            for (int t = 0; t < 4; ++t)
                xn[t] = *(const f32x4*)&xp[ch * XCH + un * XROW + t * 64 + w * 16 + q * 4];

            f32x4 g[4];
#pragma unroll
            for (int t = 0; t < 4; ++t) {
                f32x4 acc = __builtin_amdgcn_mfma_f32_16x16x32_f16(Ah[t][0], ah0, xv[t], 0, 0, 0);
                acc       = __builtin_amdgcn_mfma_f32_16x16x32_f16(Ah[t][1], ah1, acc,  0, 0, 0);
                g[t] = acc;
            }

            float hh[4];
#pragma unroll
            for (int i = 0; i < 4; ++i) {
                float e_i = frcp(1.f + ex2(g[0][i]));
                float e_f = frcp(1.f + ex2(g[1][i]));
                float tg  = TWOL - FOURL * frcp(1.f + ex2(g[2][i]));
                float e_o = frcp(1.f + ex2(g[3][i]));
                cp[i] = e_f * cp[i] + e_i * tg;
                float r = frcp(1.f + ex2(cp[i]));
                hh[i] = e_o * fmaf(-2.f, r, 1.f);
            }

            if (m < 4) {   // chain == m; replicas m>=4 hold identical values
                half4 hv;
                hv[0] = (_Float16)hh[0]; hv[1] = (_Float16)hh[1];
                hv[2] = (_Float16)hh[2]; hv[3] = (_Float16)hh[3];
                const int tg_t = dir ? (TT - 1 - (c0 + u)) : (c0 + u);
                *(half4*)&out0[((size_t)(b0 + m) * TT + tg_t) * 128 + dir * 64 + w * 16 + q * 4] = hv;
                *(half4*)&hbuf[p ^ 1][m][w * 16 + q * 4] = hv;
            }
            step_barrier();
            p ^= 1;
#pragma unroll
            for (int t = 0; t < 4; ++t) xv[t] = xn[t];
        }
    }
}

// ---------------------------------------------------------------------------
// Layer 1: same type-major structure, K=128 phase A (4 slices), mean-pool.
// ---------------------------------------------------------------------------
__global__ __launch_bounds__(256, 1) void lstm_l1(
    const _Float16* __restrict__ out0,
    const float* __restrict__ WihF, const float* __restrict__ WhhF, const float* __restrict__ bF,
    const float* __restrict__ WihB, const float* __restrict__ WhhB, const float* __restrict__ bB,
    float* __restrict__ pooled)
{
    const int dir = blockIdx.x & 1;
    const int b0  = (blockIdx.x >> 1) * 4;
    const int tid = threadIdx.x;
    const int w = tid >> 6, l = tid & 63, m = l & 15, q = l >> 4;
    const int ch = m & 3;

    const float* Wih = dir ? WihB : WihF;
    const float* Whh = dir ? WhhB : WhhF;
    const float* bia = dir ? bB   : bF;

    half8 Ah[4][2];
#pragma unroll
    for (int t = 0; t < 4; ++t) {
        const float st = (t == 2) ? TWOL : -LOG2E;
        const int wrow = t * 64 + w * 16 + m;
#pragma unroll
        for (int s2 = 0; s2 < 2; ++s2) {
            const float* src = Whh + wrow * 64 + s2 * 32 + q * 8;
            half8 tmp;
#pragma unroll
            for (int j = 0; j < 8; ++j) tmp[j] = (_Float16)(src[j] * st);
            Ah[t][s2] = tmp;
        }
    }

    const float sw = (w == 2) ? TWOL : -LOG2E;
    half8 Bg[4][4];
    float bvj[4];
#pragma unroll
    for (int j = 0; j < 4; ++j) {
        const int n = w * 64 + j * 16 + m;
        bvj[j] = bia[n] * sw;
#pragma unroll
        for (int k4 = 0; k4 < 4; ++k4) {
            const float* src = Wih + n * 128 + k4 * 32 + q * 8;
            half8 tmp;
#pragma unroll
            for (int jj = 0; jj < 8; ++jj) tmp[jj] = (_Float16)(src[jj] * sw);
            Bg[j][k4] = tmp;
        }
    }

    __shared__ __align__(16) float xp[4 * XCH];
    __shared__ __align__(16) _Float16 hbuf[2][4][CSTR];
    for (int i = tid; i < 2 * 4 * CSTR / 2; i += 256) ((unsigned int*)hbuf)[i] = 0u;
    __syncthreads();

    float cp[4] = {0.f, 0.f, 0.f, 0.f};
    float hs[4] = {0.f, 0.f, 0.f, 0.f};
    int p = 0;

    half8 a[4][4];
    {
        const int tA = dir ? (TT - 1 - m) : m;
#pragma unroll
        for (int cc = 0; cc < 4; ++cc) {
            const _Float16* arow = out0 + (size_t)((b0 + cc) * TT + tA) * 128 + q * 8;
#pragma unroll
            for (int k4 = 0; k4 < 4; ++k4)
                a[cc][k4] = *(const half8*)(arow + k4 * 32);
        }
    }

    for (int chunk = 0; chunk < NCHUNK; ++chunk) {
        const int c0 = chunk * UCH;

        // Phase A
#pragma unroll
        for (int cc = 0; cc < 4; ++cc) {
#pragma unroll
            for (int j = 0; j < 4; ++j) {
                f32x4 acc = {bvj[j], bvj[j], bvj[j], bvj[j]};
                acc = __builtin_amdgcn_mfma_f32_16x16x32_f16(a[cc][0], Bg[j][0], acc, 0, 0, 0);
                acc = __builtin_amdgcn_mfma_f32_16x16x32_f16(a[cc][1], Bg[j][1], acc, 0, 0, 0);
                acc = __builtin_amdgcn_mfma_f32_16x16x32_f16(a[cc][2], Bg[j][2], acc, 0, 0, 0);
                acc = __builtin_amdgcn_mfma_f32_16x16x32_f16(a[cc][3], Bg[j][3], acc, 0, 0, 0);
#pragma unroll
                for (int i = 0; i < 4; ++i)
                    xp[cc * XCH + (q * 4 + i) * XROW + w * 64 + j * 16 + m] = acc[i];
            }
        }
        if (chunk + 1 < NCHUNK) {
            const int tA = dir ? (TT - 1 - (c0 + UCH + m)) : (c0 + UCH + m);
#pragma unroll
            for (int cc = 0; cc < 4; ++cc) {
                const _Float16* arow = out0 + (size_t)((b0 + cc) * TT + tA) * 128 + q * 8;
#pragma unroll
                for (int k4 = 0; k4 < 4; ++k4)
                    a[cc][k4] = *(const half8*)(arow + k4 * 32);
            }
        }
        step_barrier();

        // Phase B
        f32x4 xv[4];
#pragma unroll
        for (int t = 0; t < 4; ++t)
            xv[t] = *(const f32x4*)&xp[ch * XCH + t * 64 + w * 16 + q * 4];

        for (int u = 0; u < UCH; ++u) {
            half8 ah0 = *(const half8*)&hbuf[p][ch][q * 8];
            half8 ah1 = *(const half8*)&hbuf[p][ch][32 + q * 8];

            const int un = (u + 1 < UCH) ? (u + 1) : u;
            f32x4 xn[4];
#pragma unroll
            for (int t = 0; t < 4; ++t)
                xn[t] = *(const f32x4*)&xp[ch * XCH + un * XROW + t * 64 + w * 16 + q * 4];

            f32x4 g[4];
#pragma unroll
            for (int t = 0; t < 4; ++t) {
                f32x4 acc = __builtin_amdgcn_mfma_f32_16x16x32_f16(Ah[t][0], ah0, xv[t], 0, 0, 0);
                acc       = __builtin_amdgcn_mfma_f32_16x16x32_f16(Ah[t][1], ah1, acc,  0, 0, 0);
                g[t] = acc;
            }

            float hh[4];
#pragma unroll
            for (int i = 0; i < 4; ++i) {
                float e_i = frcp(1.f + ex2(g[0][i]));
                float e_f = frcp(1.f + ex2(g[1][i]));
                float tg  = TWOL - FOURL * frcp(1.f + ex2(g[2][i]));
                float e_o = frcp(1.f + ex2(g[3][i]));
                cp[i] = e_f * cp[i] + e_i * tg;
                float r = frcp(1.f + ex2(cp[i]));
                hh[i] = e_o * fmaf(-2.f, r, 1.f);
                hs[i] += hh[i];
            }

            if (m < 4) {
                half4 hv;
                hv[0] = (_Float16)hh[0]; hv[1] = (_Float16)hh[1];
                hv[2] = (_Float16)hh[2]; hv[3] = (_Float16)hh[3];
                *(half4*)&hbuf[p ^ 1][m][w * 16 + q * 4] = hv;
            }
            step_barrier();
            p ^= 1;
#pragma unroll
            for (int t = 0; t < 4; ++t) xv[t] = xn[t];
        }
    }

    if (m < 4) {
        f32x4 hv = {hs[0], hs[1], hs[2], hs[3]};
        *(f32x4*)&pooled[(size_t)(b0 + m) * 128 + dir * 64 + w * 16 + q * 4] = hv;
    }
}

// ---------------------------------------------------------------------------
// Head: out[b] = dot(pooled[b], fcw) / T + fcb
// ---------------------------------------------------------------------------
__global__ __launch_bounds__(64) void fc_head(
    const float* __restrict__ pooled,
    const float* __restrict__ fcw, const float* __restrict__ fcb,
    float* __restrict__ out)
{
    const int b = blockIdx.x;
    const int l = threadIdx.x;
    float v = pooled[b * 128 + l] * fcw[l] + pooled[b * 128 + 64 + l] * fcw[64 + l];
#pragma unroll
    for (int o = 32; o > 0; o >>= 1) v += __shfl_down(v, o);
    if (l == 0) out[b] = v * (1.f / (float)TT) + fcb[0];
}

extern "C" void kernel_launch(void* const* d_in, const int* in_sizes, int n_in,
                              void* d_out, int out_size, void* d_ws, size_t ws_size,
                              hipStream_t stream) {
    const float* x       = (const float*)d_in[0];
    const float* Wih_l0f = (const float*)d_in[1];
    const float* Whh_l0f = (const float*)d_in[2];
    const float* b_l0f   = (const float*)d_in[3];
    const float* Wih_l0b = (const float*)d_in[4];
    const float* Whh_l0b = (const float*)d_in[5];
    const float* b_l0b   = (const float*)d_in[6];
    const float* Wih_l1f = (const float*)d_in[7];
    const float* Whh_l1f = (const float*)d_in[8];
    const float* b_l1f   = (const float*)d_in[9];
    const float* Wih_l1b = (const float*)d_in[10];
    const float* Whh_l1b = (const float*)d_in[11];
    const float* b_l1b   = (const float*)d_in[12];
    const float* fcw     = (const float*)d_in[13];
    const float* fcb     = (const float*)d_in[14];

    const size_t o_xpad   = 0;
    const size_t o_out0   = o_xpad + (size_t)BB * TT * 32 * 2;
    const size_t o_pooled = o_out0 + (size_t)BB * TT * 128 * 2;

    _Float16* xpad   = (_Float16*)((char*)d_ws + o_xpad);
    _Float16* out0   = (_Float16*)((char*)d_ws + o_out0);
    float*    pooled = (float*)((char*)d_ws + o_pooled);

    xpad_prep<<<(BB * TT * 4) / 256, 256, 0, stream>>>(x, xpad);
    lstm_l0<<<(BB / 4) * 2, 256, 0, stream>>>(xpad, Wih_l0f, Whh_l0f, b_l0f,
                                              Wih_l0b, Whh_l0b, b_l0b, out0);
    lstm_l1<<<(BB / 4) * 2, 256, 0, stream>>>(out0, Wih_l1f, Whh_l1f, b_l1f,
                                              Wih_l1b, Whh_l1b, b_l1b, pooled);
    fc_head<<<BB, 64, 0, stream>>>(pooled, fcw, fcb, (float*)d_out);
}

// Round 3
// 401.766 us; speedup vs baseline: 1.3666x; 1.3666x over previous
//
#include <hip/hip_runtime.h>

#define H  64
#define TT 512
#define BB 512
#define CSTR 80             // hbuf chain stride in halves
#define UCH 16              // chunk length (steps)
#define XROW 264            // xp step-row stride in dwords (256 data + 8 pad)
#define XCH  (UCH * XROW + 8)  // per-chain xp stride in dwords
#define NCHUNK (TT / UCH)

typedef _Float16 half8 __attribute__((ext_vector_type(8)));
typedef float    f32x4 __attribute__((ext_vector_type(4)));

#define LOG2E 1.4426950408889634f
#define TWOL  2.8853900817779268f
#define FOURL 5.7707801635558536f

#define MFMA16 __builtin_amdgcn_mfma_f32_16x16x32_f16

__device__ __forceinline__ float frcp(float x) { return __builtin_amdgcn_rcpf(x); }
__device__ __forceinline__ float ex2(float x)  { return __builtin_amdgcn_exp2f(x); }

// Barrier waiting ONLY lgkmcnt (LDS visibility) — keeps global stores /
// prefetch loads (vmcnt) off the per-step critical path.
__device__ __forceinline__ void step_barrier() {
    asm volatile("s_waitcnt lgkmcnt(0)\n\ts_barrier" ::: "memory");
}

// Extract component i0 (runtime, per-lane constant) from an f32x4: 3 cndmask.
__device__ __forceinline__ float sel4(f32x4 v, bool lo, bool hi) {
    float a = lo ? v[1] : v[0];
    float b = lo ? v[3] : v[2];
    return hi ? b : a;
}

// ---------------------------------------------------------------------------
// xpad: [B*T][32] fp16, cols 0..3 = x, cols 4..31 = 0.
// ---------------------------------------------------------------------------
__global__ __launch_bounds__(256) void xpad_prep(const float* __restrict__ x,
                                                 _Float16* __restrict__ xpad) {
    int gid = blockIdx.x * 256 + threadIdx.x;
    int row = gid >> 2, q = gid & 3;
    half8 v = {0,0,0,0,0,0,0,0};
    if (q == 0) {
        float4 xv = ((const float4*)x)[row];
        v[0] = (_Float16)xv.x; v[1] = (_Float16)xv.y;
        v[2] = (_Float16)xv.z; v[3] = (_Float16)xv.w;
    }
    *(half8*)(xpad + (size_t)row * 32 + q * 8) = v;
}

// ===========================================================================
// Shared structure (both layers): 4 samples/block (one dir), grid 256 =
// 1 block/CU, 1 wave/SIMD.
//
// Phase B (per step, type-major): MFMA pair t computes gate-type t of units
// w*16+0..15 for 4 chains (cols m: ch=m&3, replica m>>2). Lane (q,m) owns
// ONE (unit,chain): unit uo=w*16+q*4+(m>>2), chain m&3 — extracts D-reg
// i0=m>>2 (3 cndmask/type), adds its unit's x (post-add, C=0-init), runs
// ONE activation set (10 trans ops). Weights pre-scaled by -log2e (i,f,o) /
// +2log2e (g); cell state kept in the 2log2e*c domain.
//
// Phase A (TRANSPOSED, interleaved): A-operand = Wih rows (16 gates = 4
// units x 4 types), B-operand = x data (cols = 16 steps). Lane (q,m)'s D
// f32x4 = the 4 TYPES of unit w*16+j*4+q at step m -> one ds_write_b128
// into unit-major xp[step][unit*4+type]. One part (cc,j) per step rides in
// the step's MFMA/act shadow, writing NEXT chunk's xp into the other
// buffer (static xpA/xpB + macro parity => clean alias analysis, no forced
// LDS ordering). a[] register double-buffer: loads issued one chunk ahead.
// ===========================================================================

#define L0_CHUNK(CIDX, XPR, XPW, AUSE, ALOAD)                                   \
    {                                                                           \
        const int c_ = (CIDX);                                                  \
        if (c_ + 2 < NCHUNK) {                                                  \
            const int tL = dir ? (TT - 1 - ((c_ + 2) * UCH + m))                \
                               : ((c_ + 2) * UCH + m);                          \
            _Pragma("unroll")                                                   \
            for (int cc = 0; cc < 4; ++cc)                                      \
                ALOAD[cc] = *(const half8*)(xpad +                              \
                    (size_t)((b0 + cc) * TT + tL) * 32 + q * 8);                \
        }                                                                       \
        _Pragma("unroll")                                                       \
        for (int u = 0; u < UCH; ++u) {                                         \
            half8 ah0 = *(const half8*)&hbuf[p][ch][q * 8];                     \
            half8 ah1 = *(const half8*)&hbuf[p][ch][32 + q * 8];                \
            f32x4 xq = *(const f32x4*)&XPR[ch * XCH + u * XROW + uo * 4];       \
            f32x4 g0 = MFMA16(Ah[0][0], ah0, vz, 0, 0, 0);                      \
            g0       = MFMA16(Ah[0][1], ah1, g0, 0, 0, 0);                      \
            f32x4 g1 = MFMA16(Ah[1][0], ah0, vz, 0, 0, 0);                      \
            g1       = MFMA16(Ah[1][1], ah1, g1, 0, 0, 0);                      \
            f32x4 g2 = MFMA16(Ah[2][0], ah0, vz, 0, 0, 0);                      \
            g2       = MFMA16(Ah[2][1], ah1, g2, 0, 0, 0);                      \
            f32x4 g3 = MFMA16(Ah[3][0], ah0, vz, 0, 0, 0);                      \
            g3       = MFMA16(Ah[3][1], ah1, g3, 0, 0, 0);                      \
            { /* phase-A part u for next chunk */                               \
                f32x4 acc = bb[u & 3];                                          \
                acc = MFMA16(Wg[u & 3], AUSE[u >> 2], acc, 0, 0, 0);            \
                *(f32x4*)&XPW[(u >> 2) * XCH + m * XROW +                       \
                              (w * 16 + (u & 3) * 4 + q) * 4] = acc;            \
            }                                                                   \
            float gi = sel4(g0, sLo, sHi) + xq[0];                              \
            float gf = sel4(g1, sLo, sHi) + xq[1];                              \
            float gg = sel4(g2, sLo, sHi) + xq[2];                              \
            float go = sel4(g3, sLo, sHi) + xq[3];                              \
            float e_i = frcp(1.f + ex2(gi));                                    \
            float e_f = frcp(1.f + ex2(gf));                                    \
            float tg  = TWOL - FOURL * frcp(1.f + ex2(gg));                     \
            float e_o = frcp(1.f + ex2(go));                                    \
            cp = e_f * cp + e_i * tg;                                           \
            float hh = e_o * fmaf(-2.f, frcp(1.f + ex2(cp)), 1.f);              \
            const int tg_t = dir ? (TT - 1 - (c_ * UCH + u)) : (c_ * UCH + u);  \
            out0[((size_t)(b0 + ch) * TT + tg_t) * 128 + dir * 64 + uo] =       \
                (_Float16)hh;                                                   \
            hbuf[p ^ 1][ch][uo] = (_Float16)hh;                                 \
            step_barrier();                                                     \
            p ^= 1;                                                             \
        }                                                                       \
    }

__global__ __launch_bounds__(256, 1) void lstm_l0(
    const _Float16* __restrict__ xpad,
    const float* __restrict__ WihF, const float* __restrict__ WhhF, const float* __restrict__ bF,
    const float* __restrict__ WihB, const float* __restrict__ WhhB, const float* __restrict__ bB,
    _Float16* __restrict__ out0)
{
    const int dir = blockIdx.x & 1;
    const int b0  = (blockIdx.x >> 1) * 4;
    const int tid = threadIdx.x;
    const int w = tid >> 6, l = tid & 63, m = l & 15, q = l >> 4;
    const int ch = m & 3;
    const int i0 = m >> 2;
    const int uo = w * 16 + q * 4 + i0;
    const bool sLo = (i0 & 1) != 0, sHi = (i0 & 2) != 0;

    const float* Wih = dir ? WihB : WihF;
    const float* Whh = dir ? WhhB : WhhF;
    const float* bia = dir ? bB   : bF;

    // Phase-B A-operand: type-major Whh rows t*64 + w*16 + m.
    half8 Ah[4][2];
#pragma unroll
    for (int t = 0; t < 4; ++t) {
        const float st = (t == 2) ? TWOL : -LOG2E;
        const int wrow = t * 64 + w * 16 + m;
#pragma unroll
        for (int s2 = 0; s2 < 2; ++s2) {
            const float* src = Whh + wrow * 64 + s2 * 32 + q * 8;
            half8 tmp;
#pragma unroll
            for (int j = 0; j < 8; ++j) tmp[j] = (_Float16)(src[j] * st);
            Ah[t][s2] = tmp;
        }
    }

    // Phase-A A-operand (weights): row m of block j = gate
    // (type m&3, unit w*16 + j*4 + (m>>2)); K=4 padded to 32.
    const float sm = ((m & 3) == 2) ? TWOL : -LOG2E;
    half8 Wg[4];
#pragma unroll
    for (int j = 0; j < 4; ++j) {
        const int gr = (m & 3) * 64 + w * 16 + j * 4 + (m >> 2);
        half8 tmp;
#pragma unroll
        for (int jj = 0; jj < 8; ++jj) {
            int k = q * 8 + jj;
            tmp[jj] = (k < 4) ? (_Float16)(Wih[gr * 4 + k] * sm) : (_Float16)0.f;
        }
        Wg[j] = tmp;
    }

    // Bias C-init: bb[j][i] = bias[type i, unit w*16 + j*4 + q] * scale(i).
    f32x4 bb[4];
#pragma unroll
    for (int j = 0; j < 4; ++j) {
        const int ub = w * 16 + j * 4 + q;
        bb[j][0] = bia[ub]       * -LOG2E;
        bb[j][1] = bia[64 + ub]  * -LOG2E;
        bb[j][2] = bia[128 + ub] * TWOL;
        bb[j][3] = bia[192 + ub] * -LOG2E;
    }

    const f32x4 vz = {0.f, 0.f, 0.f, 0.f};

    __shared__ __align__(16) float xpA[4 * XCH];   // 67.7 KB
    __shared__ __align__(16) float xpB[4 * XCH];   // 67.7 KB
    __shared__ __align__(16) _Float16 hbuf[2][4][CSTR];
    for (int i = tid; i < 2 * 4 * CSTR / 2; i += 256) ((unsigned int*)hbuf)[i] = 0u;

    float cp = 0.f;
    int p = 0;

    half8 aR[2][4];
    // Prologue: chunk-0 data -> aR[0] (consumed now), chunk-1 data -> aR[1]
    // (used by parts during chunk 0). Then phase A for chunk 0 into xpA.
    {
        const int t0 = dir ? (TT - 1 - m) : m;
        const int t1 = dir ? (TT - 1 - (UCH + m)) : (UCH + m);
#pragma unroll
        for (int cc = 0; cc < 4; ++cc) {
            aR[0][cc] = *(const half8*)(xpad + (size_t)((b0 + cc) * TT + t0) * 32 + q * 8);
            aR[1][cc] = *(const half8*)(xpad + (size_t)((b0 + cc) * TT + t1) * 32 + q * 8);
        }
#pragma unroll
        for (int pp = 0; pp < 16; ++pp) {
            const int cc = pp >> 2, j = pp & 3;
            f32x4 acc = bb[j];
            acc = MFMA16(Wg[j], aR[0][cc], acc, 0, 0, 0);
            *(f32x4*)&xpA[cc * XCH + m * XROW + (w * 16 + j * 4 + q) * 4] = acc;
        }
        __syncthreads();
    }

    for (int c = 0; c < NCHUNK; c += 2) {
        L0_CHUNK(c,     xpA, xpB, aR[1], aR[0]);
        L0_CHUNK(c + 1, xpB, xpA, aR[0], aR[1]);
    }
}

// ---------------------------------------------------------------------------
// Layer 1: identical structure, K=128 phase A (4 k-slices per part), mean-pool.
// ---------------------------------------------------------------------------
#define L1_CHUNK(CIDX, XPR, XPW, AUSE, ALOAD)                                   \
    {                                                                           \
        const int c_ = (CIDX);                                                  \
        if (c_ + 2 < NCHUNK) {                                                  \
            const int tL = dir ? (TT - 1 - ((c_ + 2) * UCH + m))                \
                               : ((c_ + 2) * UCH + m);                          \
            _Pragma("unroll")                                                   \
            for (int cc = 0; cc < 4; ++cc) {                                    \
                const _Float16* arow = out0 +                                   \
                    (size_t)((b0 + cc) * TT + tL) * 128 + q * 8;                \
                _Pragma("unroll")                                               \
                for (int k4 = 0; k4 < 4; ++k4)                                  \
                    ALOAD[cc][k4] = *(const half8*)(arow + k4 * 32);            \
            }                                                                   \
        }                                                                       \
        _Pragma("unroll")                                                       \
        for (int u = 0; u < UCH; ++u) {                                         \
            half8 ah0 = *(const half8*)&hbuf[p][ch][q * 8];                     \
            half8 ah1 = *(const half8*)&hbuf[p][ch][32 + q * 8];                \
            f32x4 xq = *(const f32x4*)&XPR[ch * XCH + u * XROW + uo * 4];       \
            f32x4 g0 = MFMA16(Ah[0][0], ah0, vz, 0, 0, 0);                      \
            g0       = MFMA16(Ah[0][1], ah1, g0, 0, 0, 0);                      \
            f32x4 g1 = MFMA16(Ah[1][0], ah0, vz, 0, 0, 0);                      \
            g1       = MFMA16(Ah[1][1], ah1, g1, 0, 0, 0);                      \
            f32x4 g2 = MFMA16(Ah[2][0], ah0, vz, 0, 0, 0);                      \
            g2       = MFMA16(Ah[2][1], ah1, g2, 0, 0, 0);                      \
            f32x4 g3 = MFMA16(Ah[3][0], ah0, vz, 0, 0, 0);                      \
            g3       = MFMA16(Ah[3][1], ah1, g3, 0, 0, 0);                      \
            { /* phase-A part u: 4 K-slices */                                  \
                f32x4 acc = bb[u & 3];                                          \
                acc = MFMA16(Wg[u & 3][0], AUSE[u >> 2][0], acc, 0, 0, 0);      \
                acc = MFMA16(Wg[u & 3][1], AUSE[u >> 2][1], acc, 0, 0, 0);      \
                acc = MFMA16(Wg[u & 3][2], AUSE[u >> 2][2], acc, 0, 0, 0);      \
                acc = MFMA16(Wg[u & 3][3], AUSE[u >> 2][3], acc, 0, 0, 0);      \
                *(f32x4*)&XPW[(u >> 2) * XCH + m * XROW +                       \
                              (w * 16 + (u & 3) * 4 + q) * 4] = acc;            \
            }                                                                   \
            float gi = sel4(g0, sLo, sHi) + xq[0];                              \
            float gf = sel4(g1, sLo, sHi) + xq[1];                              \
            float gg = sel4(g2, sLo, sHi) + xq[2];                              \
            float go = sel4(g3, sLo, sHi) + xq[3];                              \
            float e_i = frcp(1.f + ex2(gi));                                    \
            float e_f = frcp(1.f + ex2(gf));                                    \
            float tg  = TWOL - FOURL * frcp(1.f + ex2(gg));                     \
            float e_o = frcp(1.f + ex2(go));                                    \
            cp = e_f * cp + e_i * tg;                                           \
            float hh = e_o * fmaf(-2.f, frcp(1.f + ex2(cp)), 1.f);              \
            hs += hh;                                                           \
            hbuf[p ^ 1][ch][uo] = (_Float16)hh;                                 \
            step_barrier();                                                     \
            p ^= 1;                                                             \
        }                                                                       \
    }

__global__ __launch_bounds__(256, 1) void lstm_l1(
    const _Float16* __restrict__ out0,
    const float* __restrict__ WihF, const float* __restrict__ WhhF, const float* __restrict__ bF,
    const float* __restrict__ WihB, const float* __restrict__ WhhB, const float* __restrict__ bB,
    float* __restrict__ pooled)
{
    const int dir = blockIdx.x & 1;
    const int b0  = (blockIdx.x >> 1) * 4;
    const int tid = threadIdx.x;
    const int w = tid >> 6, l = tid & 63, m = l & 15, q = l >> 4;
    const int ch = m & 3;
    const int i0 = m >> 2;
    const int uo = w * 16 + q * 4 + i0;
    const bool sLo = (i0 & 1) != 0, sHi = (i0 & 2) != 0;

    const float* Wih = dir ? WihB : WihF;
    const float* Whh = dir ? WhhB : WhhF;
    const float* bia = dir ? bB   : bF;

    half8 Ah[4][2];
#pragma unroll
    for (int t = 0; t < 4; ++t) {
        const float st = (t == 2) ? TWOL : -LOG2E;
        const int wrow = t * 64 + w * 16 + m;
#pragma unroll
        for (int s2 = 0; s2 < 2; ++s2) {
            const float* src = Whh + wrow * 64 + s2 * 32 + q * 8;
            half8 tmp;
#pragma unroll
            for (int j = 0; j < 8; ++j) tmp[j] = (_Float16)(src[j] * st);
            Ah[t][s2] = tmp;
        }
    }

    const float sm = ((m & 3) == 2) ? TWOL : -LOG2E;
    half8 Wg[4][4];
#pragma unroll
    for (int j = 0; j < 4; ++j) {
        const int gr = (m & 3) * 64 + w * 16 + j * 4 + (m >> 2);
#pragma unroll
        for (int k4 = 0; k4 < 4; ++k4) {
            const float* src = Wih + gr * 128 + k4 * 32 + q * 8;
            half8 tmp;
#pragma unroll
            for (int jj = 0; jj < 8; ++jj) tmp[jj] = (_Float16)(src[jj] * sm);
            Wg[j][k4] = tmp;
        }
    }

    f32x4 bb[4];
#pragma unroll
    for (int j = 0; j < 4; ++j) {
        const int ub = w * 16 + j * 4 + q;
        bb[j][0] = bia[ub]       * -LOG2E;
        bb[j][1] = bia[64 + ub]  * -LOG2E;
        bb[j][2] = bia[128 + ub] * TWOL;
        bb[j][3] = bia[192 + ub] * -LOG2E;
    }

    const f32x4 vz = {0.f, 0.f, 0.f, 0.f};

    __shared__ __align__(16) float xpA[4 * XCH];
    __shared__ __align__(16) float xpB[4 * XCH];
    __shared__ __align__(16) _Float16 hbuf[2][4][CSTR];
    for (int i = tid; i < 2 * 4 * CSTR / 2; i += 256) ((unsigned int*)hbuf)[i] = 0u;

    float cp = 0.f, hs = 0.f;
    int p = 0;

    half8 aR[2][4][4];
    {
        const int t0 = dir ? (TT - 1 - m) : m;
        const int t1 = dir ? (TT - 1 - (UCH + m)) : (UCH + m);
#pragma unroll
        for (int cc = 0; cc < 4; ++cc) {
            const _Float16* r0 = out0 + (size_t)((b0 + cc) * TT + t0) * 128 + q * 8;
            const _Float16* r1 = out0 + (size_t)((b0 + cc) * TT + t1) * 128 + q * 8;
#pragma unroll
            for (int k4 = 0; k4 < 4; ++k4) {
                aR[0][cc][k4] = *(const half8*)(r0 + k4 * 32);
                aR[1][cc][k4] = *(const half8*)(r1 + k4 * 32);
            }
        }
#pragma unroll
        for (int pp = 0; pp < 16; ++pp) {
            const int cc = pp >> 2, j = pp & 3;
            f32x4 acc = bb[j];
            acc = MFMA16(Wg[j][0], aR[0][cc][0], acc, 0, 0, 0);
            acc = MFMA16(Wg[j][1], aR[0][cc][1], acc, 0, 0, 0);
            acc = MFMA16(Wg[j][2], aR[0][cc][2], acc, 0, 0, 0);
            acc = MFMA16(Wg[j][3], aR[0][cc][3], acc, 0, 0, 0);
            *(f32x4*)&xpA[cc * XCH + m * XROW + (w * 16 + j * 4 + q) * 4] = acc;
        }
        __syncthreads();
    }

    for (int c = 0; c < NCHUNK; c += 2) {
        L1_CHUNK(c,     xpA, xpB, aR[1], aR[0]);
        L1_CHUNK(c + 1, xpB, xpA, aR[0], aR[1]);
    }

    pooled[(size_t)(b0 + ch) * 128 + dir * 64 + uo] = hs;
}

// ---------------------------------------------------------------------------
// Head: out[b] = dot(pooled[b], fcw) / T + fcb
// ---------------------------------------------------------------------------
__global__ __launch_bounds__(64) void fc_head(
    const float* __restrict__ pooled,
    const float* __restrict__ fcw, const float* __restrict__ fcb,
    float* __restrict__ out)
{
    const int b = blockIdx.x;
    const int l = threadIdx.x;
    float v = pooled[b * 128 + l] * fcw[l] + pooled[b * 128 + 64 + l] * fcw[64 + l];
#pragma unroll
    for (int o = 32; o > 0; o >>= 1) v += __shfl_down(v, o);
    if (l == 0) out[b] = v * (1.f / (float)TT) + fcb[0];
}

extern "C" void kernel_launch(void* const* d_in, const int* in_sizes, int n_in,
                              void* d_out, int out_size, void* d_ws, size_t ws_size,
                              hipStream_t stream) {
    const float* x       = (const float*)d_in[0];
    const float* Wih_l0f = (const float*)d_in[1];
    const float* Whh_l0f = (const float*)d_in[2];
    const float* b_l0f   = (const float*)d_in[3];
    const float* Wih_l0b = (const float*)d_in[4];
    const float* Whh_l0b = (const float*)d_in[5];
    const float* b_l0b   = (const float*)d_in[6];
    const float* Wih_l1f = (const float*)d_in[7];
    const float* Whh_l1f = (const float*)d_in[8];
    const float* b_l1f   = (const float*)d_in[9];
    const float* Wih_l1b = (const float*)d_in[10];
    const float* Whh_l1b = (const float*)d_in[11];
    const float* b_l1b   = (const float*)d_in[12];
    const float* fcw     = (const float*)d_in[13];
    const float* fcb     = (const float*)d_in[14];

    const size_t o_xpad   = 0;
    const size_t o_out0   = o_xpad + (size_t)BB * TT * 32 * 2;
    const size_t o_pooled = o_out0 + (size_t)BB * TT * 128 * 2;

    _Float16* xpad   = (_Float16*)((char*)d_ws + o_xpad);
    _Float16* out0   = (_Float16*)((char*)d_ws + o_out0);
    float*    pooled = (float*)((char*)d_ws + o_pooled);

    xpad_prep<<<(BB * TT * 4) / 256, 256, 0, stream>>>(x, xpad);
    lstm_l0<<<(BB / 4) * 2, 256, 0, stream>>>(xpad, Wih_l0f, Whh_l0f, b_l0f,
                                              Wih_l0b, Whh_l0b, b_l0b, out0);
    lstm_l1<<<(BB / 4) * 2, 256, 0, stream>>>(out0, Wih_l1f, Whh_l1f, b_l1f,
                                              Wih_l1b, Whh_l1b, b_l1b, pooled);
    fc_head<<<BB, 64, 0, stream>>>(pooled, fcw, fcb, (float*)d_out);
}